// Round 1
// 387.448 us; speedup vs baseline: 1.0668x; 1.0668x over previous
//
#include <hip/hip_runtime.h>

// Problem constants (from reference setup_inputs)
constexpr int B = 2, C = 256, H = 200, W = 336;
constexpr int HW = H * W;
constexpr int OH = 14, OW = 14, OHW = OH * OW;   // 196 samples per ROI
constexpr float SCALE = 0.25f;
constexpr int R = 1000;

// CSPLIT=16: concurrent L2 working set per XCD = ~11 adjacent ROIs x 256ch
// ~= 3.5MB < 4MB L2 (CSPLIT=4 was ~63MB -> thrash, FETCH 2.9x unique).
constexpr int CSPLIT = 16;           // channel slices per ROI
constexpr int CPB = C / CSPLIT;      // 16 channels per block
constexpr int NXCD = 8;
constexpr int RPX = R / NXCD;        // 125 ROIs per XCD

// Bucket grid for the counting sort (locality only needs band-level order)
constexpr int NYB = 13;              // 64-px y bands over 800 px
constexpr int NXB = 21;              // 64-px x bands over 1344 px
constexpr int NBUCKET = B * NYB * NXB;   // 546 <= 1024

// 8-byte pair load with only 4-byte alignment guarantee.
typedef float f2 __attribute__((ext_vector_type(2), aligned(4)));

// ---------------------------------------------------------------------------
// Kernel A: counting sort of ROI indices into (batch, y-band, x-band) buckets.
// Replaces the 55-stage bitonic sort; any within-bucket permutation is
// numerically identical downstream (order only steers L2 locality).
// ---------------------------------------------------------------------------
__global__ __launch_bounds__(1024) void bucket_rois_kernel(
    const float* __restrict__ rois, int* __restrict__ order)
{
    __shared__ int cnt[1024];
    const int t = threadIdx.x;
    cnt[t] = 0;
    __syncthreads();

    int k = 0, pos = 0;
    if (t < R) {
        const float* roi = rois + t * 5;
        const int   b  = (int)roi[0];
        const float cx = 0.5f * (roi[1] + roi[3]);
        const float cy = 0.5f * (roi[2] + roi[4]);
        const int yb = min(NYB - 1, max(0, (int)cy >> 6));
        const int xb = min(NXB - 1, max(0, (int)cx >> 6));
        k = (b * NYB + yb) * NXB + xb;
        pos = atomicAdd(&cnt[k], 1);      // rank within bucket
    }
    __syncthreads();

    // Inclusive Hillis-Steele scan over the 1024 bucket counts.
    for (int off = 1; off < 1024; off <<= 1) {
        const int add = (t >= off) ? cnt[t - off] : 0;
        __syncthreads();
        cnt[t] += add;
        __syncthreads();
    }

    if (t < R) {
        const int base = (k > 0) ? cnt[k - 1] : 0;  // exclusive prefix
        order[base + pos] = t;
    }
}

// ---------------------------------------------------------------------------
// Kernel B: ROI-Align. blockIdx%8 pins a spatial ROI chunk to one XCD; slice
// index is innermost so all 16 slices (256 channels) of ~11 adjacent ROIs are
// co-resident -> concurrent feature working set fits the 4MB per-XCD L2.
// Loads are issued in explicit 8-channel batches (16 loads in flight/thread)
// to deepen the memory pipeline (old VGPR=24 build kept only ~2-4 in flight).
// ---------------------------------------------------------------------------
__global__ __launch_bounds__(256, 8) void roi_align_kernel(
    const float* __restrict__ feat,   // (B, C, H, W)
    const float* __restrict__ rois,   // (R, 5)
    const int*  __restrict__ order,   // (R) spatially bucketed ROI indices
    float* __restrict__ out)          // (R, C, OH, OW)
{
    const int bid   = blockIdx.x;
    const int xcd   = bid & (NXCD - 1);       // dispatch round-robins XCDs
    const int slot  = bid >> 3;               // 0..(RPX*CSPLIT-1)
    const int slice = slot & (CSPLIT - 1);    // slice inner: all 16 slices of
    const int rank  = slot >> 4;              // adjacent ROIs co-resident
    const int r     = __builtin_amdgcn_readfirstlane(order[xcd * RPX + rank]);
    const int c0    = slice * CPB;
    const int s     = threadIdx.x;

    const float* roi = rois + r * 5;
    const float bf = roi[0];
    const float x1 = roi[1], y1 = roi[2], x2 = roi[3], y2 = roi[4];
    const int b = __builtin_amdgcn_readfirstlane((int)bf);

    if (s >= OHW) return;            // lanes 196..255 idle

    const int oh = s / OW;
    const int ow = s - oh * OW;

    // Sample position in feature space (matches reference exactly)
    const float fx = (x1 + (ow + 0.5f) * (1.0f / OW) * (x2 - x1)) * SCALE - 0.5f;
    const float fy = (y1 + (oh + 0.5f) * (1.0f / OH) * (y2 - y1)) * SCALE - 0.5f;

    const float x0f = floorf(fx), y0f = floorf(fy);
    const float lx = fx - x0f,   ly = fy - y0f;
    const int x0 = (int)x0f,  y0 = (int)y0f;
    const int x1i = x0 + 1,   y1i = y0 + 1;

    // Validity folded into weights (reference: v * valid)
    const float cxw0 = ((x0  >= 0 && x0  < W) ? 1.0f : 0.0f) * (1.0f - lx);
    const float cxw1 = ((x1i >= 0 && x1i < W) ? 1.0f : 0.0f) * lx;
    const float ryw0 = ((y0  >= 0 && y0  < H) ? 1.0f : 0.0f) * (1.0f - ly);
    const float ryw1 = ((y1i >= 0 && y1i < H) ? 1.0f : 0.0f) * ly;

    // Pair base clamped so [px, px+1] stays in-row; pre-swap weights if
    // clamped (invalid corner's weight is already 0, so swap is lossless).
    const int px = min(max(x0, 0), W - 2);
    const bool swp = (x0 != px);
    const float wxa = swp ? cxw1 : cxw0;
    const float wxb = swp ? cxw0 : cxw1;
    const float a0 = ryw0 * wxa, b0 = ryw0 * wxb;
    const float a1 = ryw1 * wxa, b1 = ryw1 * wxb;

    const int cy0 = min(max(y0,  0), H - 1);
    const int cy1 = min(max(y1i, 0), H - 1);
    const int i0 = cy0 * W + px;
    const int i1 = cy1 * W + px;

    const float* p  = feat + (size_t)(b * C + c0) * HW;
    float*       op = out  + (size_t)r * C * OHW + (size_t)c0 * OHW + s;

    // Two batches of 8 channels; each batch issues its 16 dwordx2 loads
    // before any consumer so the compiler keeps them all in flight.
    #pragma unroll 1
    for (int cb = 0; cb < CPB; cb += 8) {
        f2 v0[8], v1[8];
        #pragma unroll
        for (int u = 0; u < 8; ++u) {
            const float* pc = p + (size_t)u * HW;
            v0[u] = *reinterpret_cast<const f2*>(pc + i0);  // v00, v01
            v1[u] = *reinterpret_cast<const f2*>(pc + i1);  // v10, v11
        }
        #pragma unroll
        for (int u = 0; u < 8; ++u) {
            const float v = fmaf(a0, v0[u].x,
                            fmaf(b0, v0[u].y,
                            fmaf(a1, v1[u].x, b1 * v1[u].y)));
            // Output is write-once/never-read: evict-first so the 200MB write
            // stream doesn't push feature lines out of L2.
            __builtin_nontemporal_store(v, op + u * OHW);
        }
        p  += (size_t)8 * HW;
        op += 8 * OHW;
    }
}

extern "C" void kernel_launch(void* const* d_in, const int* in_sizes, int n_in,
                              void* d_out, int out_size, void* d_ws, size_t ws_size,
                              hipStream_t stream) {
    const float* feat = (const float*)d_in[0];
    const float* rois = (const float*)d_in[1];
    float* out = (float*)d_out;
    int* order = (int*)d_ws;         // R ints of scratch

    bucket_rois_kernel<<<1, 1024, 0, stream>>>(rois, order);

    dim3 grid(R * CSPLIT);
    dim3 block(256);
    roi_align_kernel<<<grid, block, 0, stream>>>(feat, rois, order, out);
}

// Round 2
// 383.764 us; speedup vs baseline: 1.0770x; 1.0096x over previous
//
#include <hip/hip_runtime.h>

// Problem constants (from reference setup_inputs)
constexpr int B = 2, C = 256, H = 200, W = 336;
constexpr int HW = H * W;
constexpr int OH = 14, OW = 14, OHW = OH * OW;   // 196 samples per ROI
constexpr float SCALE = 0.25f;
constexpr int R = 1000;

// CSPLIT=16: slices inner so all 256 channels of adjacent (bucketed) ROIs are
// co-resident on one XCD -> cross-ROI L2 reuse (R1: FETCH 400->275 MB).
constexpr int CSPLIT = 16;           // channel slices per ROI
constexpr int CPB = C / CSPLIT;      // 16 channels per block
constexpr int NXCD = 8;
constexpr int RPX = R / NXCD;        // 125 ROIs per XCD

constexpr int ITEMS = CPB * OHW;     // 3136 work items per block

// Bucket grid for the counting sort (locality only needs band-level order)
constexpr int NYB = 13;              // 64-px y bands over 800 px
constexpr int NXB = 21;              // 64-px x bands over 1344 px

// 8-byte pair load with only 4-byte alignment guarantee.
typedef float f2 __attribute__((ext_vector_type(2), aligned(4)));

// ---------------------------------------------------------------------------
// Kernel A: counting sort of ROI indices into (batch, y-band, x-band) buckets.
// ---------------------------------------------------------------------------
__global__ __launch_bounds__(1024) void bucket_rois_kernel(
    const float* __restrict__ rois, int* __restrict__ order)
{
    __shared__ int cnt[1024];
    const int t = threadIdx.x;
    cnt[t] = 0;
    __syncthreads();

    int k = 0, pos = 0;
    if (t < R) {
        const float* roi = rois + t * 5;
        const int   b  = (int)roi[0];
        const float cx = 0.5f * (roi[1] + roi[3]);
        const float cy = 0.5f * (roi[2] + roi[4]);
        const int yb = min(NYB - 1, max(0, (int)cy >> 6));
        const int xb = min(NXB - 1, max(0, (int)cx >> 6));
        k = (b * NYB + yb) * NXB + xb;
        pos = atomicAdd(&cnt[k], 1);      // rank within bucket
    }
    __syncthreads();

    // Inclusive Hillis-Steele scan over the 1024 bucket counts.
    for (int off = 1; off < 1024; off <<= 1) {
        const int add = (t >= off) ? cnt[t - off] : 0;
        __syncthreads();
        cnt[t] += add;
        __syncthreads();
    }

    if (t < R) {
        const int base = (k > 0) ? cnt[k - 1] : 0;  // exclusive prefix
        order[base + pos] = t;
    }
}

// ---------------------------------------------------------------------------
// Kernel B: ROI-Align, flattened work distribution.
//  - geometry for the 196 samples computed ONCE into LDS (SoA, stride-1,
//    conflict-free), reused across all 16 channels
//  - work = 16ch x 196 samples = 3136 items over 256 threads: zero idle lanes
//  - idx = c*196+s  ==>  output address = out_base + idx: wave stores are
//    contiguous 1KB runs (fixes R1's nontemporal partial-line write inflation)
//  - batches of 4 items issue 8 f2 loads, then sched_barrier(0) pins all
//    consumers after them: 8 loads in flight per thread for real this time
//    (R1's VGPR=24 proved the compiler interleaved them away)
// ---------------------------------------------------------------------------
__global__ __launch_bounds__(256, 8) void roi_align_kernel(
    const float* __restrict__ feat,   // (B, C, H, W)
    const float* __restrict__ rois,   // (R, 5)
    const int*  __restrict__ order,   // (R) spatially bucketed ROI indices
    float* __restrict__ out)          // (R, C, OH, OW)
{
    __shared__ int   si0[OHW], si1[OHW];
    __shared__ float sa0[OHW], sb0[OHW], sa1[OHW], sb1[OHW];

    const int bid   = blockIdx.x;
    const int xcd   = bid & (NXCD - 1);       // dispatch round-robins XCDs
    const int slot  = bid >> 3;               // 0..(RPX*CSPLIT-1)
    const int slice = slot & (CSPLIT - 1);    // slice inner: all 16 slices of
    const int rank  = slot >> 4;              // adjacent ROIs co-resident
    const int r     = __builtin_amdgcn_readfirstlane(order[xcd * RPX + rank]);
    const int c0    = slice * CPB;
    const int tid   = threadIdx.x;

    const float* roi = rois + r * 5;
    const float x1 = roi[1], y1 = roi[2], x2 = roi[3], y2 = roi[4];
    const int b = __builtin_amdgcn_readfirstlane((int)roi[0]);

    if (tid < OHW) {
        const int oh = tid / OW;
        const int ow = tid - oh * OW;

        // Sample position in feature space (matches reference exactly)
        const float fx = (x1 + (ow + 0.5f) * (1.0f / OW) * (x2 - x1)) * SCALE - 0.5f;
        const float fy = (y1 + (oh + 0.5f) * (1.0f / OH) * (y2 - y1)) * SCALE - 0.5f;

        const float x0f = floorf(fx), y0f = floorf(fy);
        const float lx = fx - x0f,   ly = fy - y0f;
        const int x0 = (int)x0f,  y0 = (int)y0f;
        const int x1i = x0 + 1,   y1i = y0 + 1;

        // Validity folded into weights (reference: v * valid)
        const float cxw0 = ((x0  >= 0 && x0  < W) ? 1.0f : 0.0f) * (1.0f - lx);
        const float cxw1 = ((x1i >= 0 && x1i < W) ? 1.0f : 0.0f) * lx;
        const float ryw0 = ((y0  >= 0 && y0  < H) ? 1.0f : 0.0f) * (1.0f - ly);
        const float ryw1 = ((y1i >= 0 && y1i < H) ? 1.0f : 0.0f) * ly;

        // Pair base clamped so [px, px+1] stays in-row; pre-swap weights if
        // clamped (invalid corner's weight is already 0, so swap is lossless).
        const int px = min(max(x0, 0), W - 2);
        const bool swp = (x0 != px);
        const float wxa = swp ? cxw1 : cxw0;
        const float wxb = swp ? cxw0 : cxw1;

        const int cy0 = min(max(y0,  0), H - 1);
        const int cy1 = min(max(y1i, 0), H - 1);

        si0[tid] = cy0 * W + px;
        si1[tid] = cy1 * W + px;
        sa0[tid] = ryw0 * wxa;
        sb0[tid] = ryw0 * wxb;
        sa1[tid] = ryw1 * wxa;
        sb1[tid] = ryw1 * wxb;
    }
    __syncthreads();

    const float* p  = feat + (size_t)(b * C + c0) * HW;
    float*       ob = out  + ((size_t)r * C + c0) * OHW;

    int idx = tid;
    // 12 full rounds = 3 batches of 4; items 3072..3135 handled in tail.
    #pragma unroll 1
    for (int bb = 0; bb < 3; ++bb) {
        const float* pa[4];
        const float* pb[4];
        float wa0[4], wb0[4], wa1[4], wb1[4];
        f2 v0[4], v1[4];

        #pragma unroll
        for (int u = 0; u < 4; ++u) {
            const int id = idx + u * 256;
            const int c  = id / OHW;           // magic-mul, no real div
            const int s  = id - c * OHW;
            const int cb = c * HW;
            pa[u] = p + cb + si0[s];
            pb[u] = p + cb + si1[s];
            wa0[u] = sa0[s]; wb0[u] = sb0[s];
            wa1[u] = sa1[s]; wb1[u] = sb1[s];
        }
        #pragma unroll
        for (int u = 0; u < 4; ++u) {
            v0[u] = *reinterpret_cast<const f2*>(pa[u]);  // v00, v01
            v1[u] = *reinterpret_cast<const f2*>(pb[u]);  // v10, v11
        }
        // Pin every consumer after the 8 loads: keeps them all in flight.
        __builtin_amdgcn_sched_barrier(0);
        #pragma unroll
        for (int u = 0; u < 4; ++u) {
            const float v = fmaf(wa0[u], v0[u].x,
                            fmaf(wb0[u], v0[u].y,
                            fmaf(wa1[u], v1[u].x, wb1[u] * v1[u].y)));
            // contiguous per-wave store run; write-once data -> evict-first
            __builtin_nontemporal_store(v, ob + idx + u * 256);
        }
        idx += 1024;
    }
    // Tail: idx = 3072 + tid, valid for tid < 64.
    if (idx < ITEMS) {
        const int c  = idx / OHW;
        const int s  = idx - c * OHW;
        const int cb = c * HW;
        const f2 r0 = *reinterpret_cast<const f2*>(p + cb + si0[s]);
        const f2 r1 = *reinterpret_cast<const f2*>(p + cb + si1[s]);
        const float v = fmaf(sa0[s], r0.x,
                        fmaf(sb0[s], r0.y,
                        fmaf(sa1[s], r1.x, sb1[s] * r1.y)));
        __builtin_nontemporal_store(v, ob + idx);
    }
}

extern "C" void kernel_launch(void* const* d_in, const int* in_sizes, int n_in,
                              void* d_out, int out_size, void* d_ws, size_t ws_size,
                              hipStream_t stream) {
    const float* feat = (const float*)d_in[0];
    const float* rois = (const float*)d_in[1];
    float* out = (float*)d_out;
    int* order = (int*)d_ws;         // R ints of scratch

    bucket_rois_kernel<<<1, 1024, 0, stream>>>(rois, order);

    dim3 grid(R * CSPLIT);
    dim3 block(256);
    roi_align_kernel<<<grid, block, 0, stream>>>(feat, rois, order, out);
}

// Round 3
// 381.141 us; speedup vs baseline: 1.0844x; 1.0069x over previous
//
#include <hip/hip_runtime.h>

// Problem constants (from reference setup_inputs)
constexpr int B = 2, C = 256, H = 200, W = 336;
constexpr int HW = H * W;
constexpr int OH = 14, OW = 14, OHW = OH * OW;   // 196 samples per ROI
constexpr float SCALE = 0.25f;
constexpr int R = 1000;

// CSPLIT=16: slices inner so all 256 channels of adjacent (bucketed) ROIs are
// co-resident on one XCD -> cross-ROI L2 reuse (R1: FETCH 400->275 MB).
constexpr int CSPLIT = 16;           // channel slices per ROI
constexpr int CPB = C / CSPLIT;      // 16 channels per block
constexpr int NXCD = 8;
constexpr int RPX = R / NXCD;        // 125 ROIs per XCD

constexpr int ITEMS = CPB * OHW;     // 3136 work items per block

// Bucket grid for the counting sort (locality only needs band-level order)
constexpr int NYB = 13;              // 64-px y bands over 800 px
constexpr int NXB = 21;              // 64-px x bands over 1344 px

// 8-byte loads: register-pair value type + 4-byte-aligned pointer type
typedef float fv2 __attribute__((ext_vector_type(2)));
typedef float f2u __attribute__((ext_vector_type(2), aligned(4)));

// ---------------------------------------------------------------------------
// Kernel A: counting sort of ROI indices into (batch, y-band, x-band) buckets.
// ---------------------------------------------------------------------------
__global__ __launch_bounds__(1024) void bucket_rois_kernel(
    const float* __restrict__ rois, int* __restrict__ order)
{
    __shared__ int cnt[1024];
    const int t = threadIdx.x;
    cnt[t] = 0;
    __syncthreads();

    int k = 0, pos = 0;
    if (t < R) {
        const float* roi = rois + t * 5;
        const int   b  = (int)roi[0];
        const float cx = 0.5f * (roi[1] + roi[3]);
        const float cy = 0.5f * (roi[2] + roi[4]);
        const int yb = min(NYB - 1, max(0, (int)cy >> 6));
        const int xb = min(NXB - 1, max(0, (int)cx >> 6));
        k = (b * NYB + yb) * NXB + xb;
        pos = atomicAdd(&cnt[k], 1);      // rank within bucket
    }
    __syncthreads();

    // Inclusive Hillis-Steele scan over the 1024 bucket counts.
    for (int off = 1; off < 1024; off <<= 1) {
        const int add = (t >= off) ? cnt[t - off] : 0;
        __syncthreads();
        cnt[t] += add;
        __syncthreads();
    }

    if (t < R) {
        const int base = (k > 0) ? cnt[k - 1] : 0;  // exclusive prefix
        order[base + pos] = t;
    }
}

// ---------------------------------------------------------------------------
// Pipeline helpers. Inline-asm global_load (SGPR base + 32-bit VGPR offset)
// so the compiler CANNOT re-serialize the batch (R1/R2: VGPR stuck at 24 ==
// proof that source-level batching was descheduled both times).
// ---------------------------------------------------------------------------
template<int BI>
__device__ __forceinline__ void issue4(const int tid, const float* p,
                                       const int2* sidx,
                                       fv2 (&V0)[4], fv2 (&V1)[4], int (&SS)[4])
{
    unsigned o0[4], o1[4];
    #pragma unroll
    for (int u = 0; u < 4; ++u) {
        const int id = tid + (BI * 4 + u) * 256;
        const int c  = id / OHW;                 // magic-mul, no real div
        const int s  = id - c * OHW;
        SS[u] = s;
        const int2 ii = sidx[s];
        const unsigned cb4 = (unsigned)c * (unsigned)(HW * 4);
        o0[u] = cb4 + (unsigned)ii.x * 4u;
        o1[u] = cb4 + (unsigned)ii.y * 4u;
    }
    #pragma unroll
    for (int u = 0; u < 4; ++u) {
        asm volatile("global_load_dwordx2 %0, %1, %2"
                     : "=v"(V0[u]) : "v"(o0[u]), "s"(p) : "memory");
        asm volatile("global_load_dwordx2 %0, %1, %2"
                     : "=v"(V1[u]) : "v"(o1[u]), "s"(p) : "memory");
    }
}

template<int BI>
__device__ __forceinline__ void consume4(const int tid, float* ob,
                                         const float4* sw,
                                         const fv2 (&V0)[4], const fv2 (&V1)[4],
                                         const int (&SS)[4])
{
    #pragma unroll
    for (int u = 0; u < 4; ++u) {
        const float4 w = sw[SS[u]];
        const float v = fmaf(w.x, V0[u].x,
                        fmaf(w.y, V0[u].y,
                        fmaf(w.z, V1[u].x, w.w * V1[u].y)));
        // contiguous per-wave run; write-once data -> evict-first
        __builtin_nontemporal_store(v, ob + tid + (BI * 4 + u) * 256);
    }
}

#define WAITV(N) do { \
    asm volatile("s_waitcnt vmcnt(" #N ")" ::: "memory"); \
    __builtin_amdgcn_sched_barrier(0); \
} while (0)

// ---------------------------------------------------------------------------
// Kernel B: ROI-Align, flattened work + 2-deep asm load pipeline.
//  - geometry computed once into LDS, packed SoA: int2 idx + float4 weights
//    (2 LDS reads/item instead of 6)
//  - 3136 items over 256 threads, zero idle lanes; out addr = base + idx so
//    wave stores are contiguous (WRITE == 196MB exact since R2)
//  - batches of 4 items = 8 dwordx2 loads issued via inline asm; counted
//    vmcnt(8) keeps the NEXT batch's 8 loads in flight across the compute
//    of the current batch: 8-16 loads in flight per wave, vs ~2 before
// ---------------------------------------------------------------------------
__global__ __launch_bounds__(256, 8) void roi_align_kernel(
    const float* __restrict__ feat,   // (B, C, H, W)
    const float* __restrict__ rois,   // (R, 5)
    const int*  __restrict__ order,   // (R) spatially bucketed ROI indices
    float* __restrict__ out)          // (R, C, OH, OW)
{
    __shared__ int2   sidx[OHW];      // (i0, i1) pixel indices
    __shared__ float4 sw[OHW];        // (a0, b0, a1, b1) corner weights

    const int bid   = blockIdx.x;
    const int xcd   = bid & (NXCD - 1);       // dispatch round-robins XCDs
    const int slot  = bid >> 3;               // 0..(RPX*CSPLIT-1)
    const int slice = slot & (CSPLIT - 1);    // slice inner: all 16 slices of
    const int rank  = slot >> 4;              // adjacent ROIs co-resident
    const int r     = __builtin_amdgcn_readfirstlane(order[xcd * RPX + rank]);
    const int c0    = slice * CPB;
    const int tid   = threadIdx.x;

    const float* roi = rois + r * 5;
    const float x1 = roi[1], y1 = roi[2], x2 = roi[3], y2 = roi[4];
    const int b = __builtin_amdgcn_readfirstlane((int)roi[0]);

    if (tid < OHW) {
        const int oh = tid / OW;
        const int ow = tid - oh * OW;

        // Sample position in feature space (matches reference exactly)
        const float fx = (x1 + (ow + 0.5f) * (1.0f / OW) * (x2 - x1)) * SCALE - 0.5f;
        const float fy = (y1 + (oh + 0.5f) * (1.0f / OH) * (y2 - y1)) * SCALE - 0.5f;

        const float x0f = floorf(fx), y0f = floorf(fy);
        const float lx = fx - x0f,   ly = fy - y0f;
        const int x0 = (int)x0f,  y0 = (int)y0f;
        const int x1i = x0 + 1,   y1i = y0 + 1;

        // Validity folded into weights (reference: v * valid)
        const float cxw0 = ((x0  >= 0 && x0  < W) ? 1.0f : 0.0f) * (1.0f - lx);
        const float cxw1 = ((x1i >= 0 && x1i < W) ? 1.0f : 0.0f) * lx;
        const float ryw0 = ((y0  >= 0 && y0  < H) ? 1.0f : 0.0f) * (1.0f - ly);
        const float ryw1 = ((y1i >= 0 && y1i < H) ? 1.0f : 0.0f) * ly;

        // Pair base clamped so [px, px+1] stays in-row; pre-swap weights if
        // clamped (invalid corner's weight is already 0, so swap is lossless).
        const int px = min(max(x0, 0), W - 2);
        const bool swp = (x0 != px);
        const float wxa = swp ? cxw1 : cxw0;
        const float wxb = swp ? cxw0 : cxw1;

        const int cy0 = min(max(y0,  0), H - 1);
        const int cy1 = min(max(y1i, 0), H - 1);

        sidx[tid] = make_int2(cy0 * W + px, cy1 * W + px);
        sw[tid]   = make_float4(ryw0 * wxa, ryw0 * wxb, ryw1 * wxa, ryw1 * wxb);
    }
    __syncthreads();   // also drains vmcnt -> loop enters with vmcnt == 0

    const float* p  = feat + (size_t)(b * C + c0) * HW;
    float*       ob = out  + ((size_t)r * C + c0) * OHW;

    // 12 full rounds = 3 batches of 4, software-pipelined 2 deep.
    fv2 xa[4], xb[4]; int xs[4];
    fv2 ya[4], yb[4]; int ys[4];

    issue4<0>(tid, p, sidx, xa, xb, xs);   // 8 loads in flight
    issue4<1>(tid, p, sidx, ya, yb, ys);   // 16 in flight
    WAITV(8);                              // batch 0 ready, batch 1 flying
    consume4<0>(tid, ob, sw, xa, xb, xs);
    issue4<2>(tid, p, sidx, xa, xb, xs);   // refill to 16 (+4 stores)
    WAITV(8);                              // batch 1 ready (drains stores too)
    consume4<1>(tid, ob, sw, ya, yb, ys);
    WAITV(0);                              // batch 2 ready
    consume4<2>(tid, ob, sw, xa, xb, xs);

    // Tail: items 3072..3135, one per thread for tid < 64.
    if (tid < 64) {
        const int idx = 3072 + tid;
        const int c  = idx / OHW;
        const int s  = idx - c * OHW;
        const int cb = c * HW;
        const int2  ii = sidx[s];
        const float4 w = sw[s];
        const f2u r0 = *reinterpret_cast<const f2u*>(p + cb + ii.x);
        const f2u r1 = *reinterpret_cast<const f2u*>(p + cb + ii.y);
        const float v = fmaf(w.x, r0.x,
                        fmaf(w.y, r0.y,
                        fmaf(w.z, r1.x, w.w * r1.y)));
        __builtin_nontemporal_store(v, ob + idx);
    }
}

extern "C" void kernel_launch(void* const* d_in, const int* in_sizes, int n_in,
                              void* d_out, int out_size, void* d_ws, size_t ws_size,
                              hipStream_t stream) {
    const float* feat = (const float*)d_in[0];
    const float* rois = (const float*)d_in[1];
    float* out = (float*)d_out;
    int* order = (int*)d_ws;         // R ints of scratch

    bucket_rois_kernel<<<1, 1024, 0, stream>>>(rois, order);

    dim3 grid(R * CSPLIT);
    dim3 block(256);
    roi_align_kernel<<<grid, block, 0, stream>>>(feat, rois, order, out);
}